// Round 15
// baseline (377.811 us; speedup 1.0000x reference)
//
#include <hip/hip_runtime.h>
#include <math.h>

#define NN 50000
#define NE 1600000
#define KORD 5
#define NB 196          // ceil(NN/256)
#define QTR 12500       // node quarter (k_deg)
#define GE 782          // epi grid: ceil(NN/64)
#define MT 64           // epi node tile
#define NBK 1563        // ceil(NN/32) destination buckets (32 nodes each)
#define NBP 1600        // padded bucket stride
#define NCH 256         // chunks for bucket kernels (fills all CUs)
#define ECH (NE / NCH)  // 6250
#define EC4 (NE / 64)   // 25000 (k_deg chunks)
#define PADE 1800192    // edge buffer capacity (NE + NBK*128, rounded)

#define SCALE_W 2097152.0f          // 2^21 spmm fixed point
#define INV_SCALE_W (1.0f / 2097152.0f)
#define SCALE_D 4194304.0f          // 2^22 degree fixed point
#define INV_SCALE_D (1.0f / 4194304.0f)

typedef _Float16 half8 __attribute__((ext_vector_type(8)));
typedef _Float16 half4v __attribute__((ext_vector_type(4)));
typedef float float4v __attribute__((ext_vector_type(4)));

// ---------------- deg: LDS int-fixed-point weighted row histogram ----------
__global__ __launch_bounds__(1024) void k_deg(const int* __restrict__ ei,
                                              const float* __restrict__ ew,
                                              int* __restrict__ deg_g) {
    __shared__ int h[QTR];   // 50 KB
    int q = blockIdx.x >> 6, ch = blockIdx.x & 63;
    for (int i = threadIdx.x; i < QTR; i += 1024) h[i] = 0;
    __syncthreads();
    int base = ch * EC4, lo = q * QTR;
    for (int e = base + threadIdx.x; e < base + EC4; e += 1024) {
        int li = ei[e] - lo;
        if ((unsigned)li < (unsigned)QTR)
            atomicAdd(&h[li], __float2int_rn(ew[e] * SCALE_D));  // ds_add_u32
    }
    __syncthreads();
    int* outp = deg_g + blockIdx.x * QTR;
    for (int i = threadIdx.x; i < QTR; i += 1024) outp[i] = h[i];
}

__global__ __launch_bounds__(256) void k_dis2(const int* __restrict__ deg_g,
                                              float* __restrict__ dis) {
    int n = blockIdx.x * 256 + threadIdx.x;
    if (n >= NN) return;
    int q = n / QTR, i = n % QTR;
    const int* p = deg_g + (q * 64) * QTR + i;
    int s = 0;
#pragma unroll
    for (int c = 0; c < 64; c++) s += p[c * QTR];
    float d = (float)s * INV_SCALE_D;
    dis[n] = s > 0 ? rsqrtf(fmaxf(d, 1e-30f)) : 0.f;
}

// ---------------- bucket histogram: bh[ch][b] ----------
__global__ __launch_bounds__(1024) void k_bhist(const int* __restrict__ ei,
                                                int* __restrict__ bh) {
    __shared__ int hist[NBK];
    int ch = blockIdx.x;
    for (int i = threadIdx.x; i < NBK; i += 1024) hist[i] = 0;
    __syncthreads();
    const int* cols = ei + NE;
    int base = ch * ECH;
    for (int e = base + threadIdx.x; e < base + ECH; e += 1024)
        atomicAdd(&hist[cols[e] >> 5], 1);
    __syncthreads();
    int* outp = bh + ch * NBP;
    for (int b = threadIdx.x; b < NBK; b += 1024) outp[b] = hist[b];
}

__global__ __launch_bounds__(256) void k_btot(const int* __restrict__ bh,
                                              int* __restrict__ tot) {
    int b = blockIdx.x * 256 + threadIdx.x;
    if (b >= NBP) return;
    int s = 0;
    if (b < NBK) {
#pragma unroll 8
        for (int ch = 0; ch < NCH; ch++) s += bh[ch * NBP + b];
    }
    tot[b] = s;
}

// one block: pair-compressed exclusive scan of PADDED totals -> off_bk
__global__ __launch_bounds__(1024) void k_bscan1(const int* __restrict__ tot,
                                                 int* __restrict__ off_bk) {
    __shared__ int s[1024];
    int t = threadIdx.x;
    int a0 = (2 * t < NBP) ? tot[2 * t] : 0;
    int a1 = (2 * t + 1 < NBP) ? tot[2 * t + 1] : 0;
    int p0 = (a0 + 127) & ~127;
    int p1 = (a1 + 127) & ~127;
    s[t] = p0 + p1;
    __syncthreads();
    for (int d = 1; d < 1024; d <<= 1) {
        int u = (t >= d) ? s[t - d] : 0;
        __syncthreads();
        s[t] += u;
        __syncthreads();
    }
    int excl = (t == 0) ? 0 : s[t - 1];
    if (2 * t < NBK) off_bk[2 * t] = excl;
    if (2 * t + 1 < NBK) off_bk[2 * t + 1] = excl + p0;
    if (t == 1023) off_bk[NBK] = s[1023];
}

__global__ __launch_bounds__(256) void k_bcur(int* __restrict__ bh,
                                              const int* __restrict__ off_bk) {
    int b = blockIdx.x * 256 + threadIdx.x;
    if (b >= NBK) return;
    int run = off_bk[b];
    for (int ch = 0; ch < NCH; ch++) {
        int v = bh[ch * NBP + b];
        bh[ch * NBP + b] = run;
        run += v;
    }
}

// fill pad region of each bucket with zero-weight sentinel edges
__global__ __launch_bounds__(128) void k_pad(const int* __restrict__ off_bk,
                                             const int* __restrict__ tot,
                                             int2* __restrict__ edges) {
    int b = blockIdx.x;
    int start = off_bk[b] + tot[b];
    int end = off_bk[b + 1];
    for (int i = start + threadIdx.x; i < end; i += 128)
        edges[i] = make_int2(0, 0);   // r=0, c_local=0, w=0.0f
}

// coarse permute: record = (r | local_c<<16, weight-bits)
__global__ __launch_bounds__(1024) void k_cperm(const int* __restrict__ ei,
                                                const float* __restrict__ ew,
                                                const float* __restrict__ dis,
                                                const int* __restrict__ bh,
                                                int2* __restrict__ edges) {
    __shared__ int cur[NBK];
    int ch = blockIdx.x;
    const int* cp = bh + ch * NBP;
    for (int b = threadIdx.x; b < NBK; b += 1024) cur[b] = cp[b];
    __syncthreads();
    int base = ch * ECH;
    for (int e = base + threadIdx.x; e < base + ECH; e += 1024) {
        int r = ei[e], c = ei[NE + e];
        float w = -dis[r] * ew[e] * dis[c];
        int pos = atomicAdd(&cur[c >> 5], 1);   // ds_add_u32, native
        int packed = (int)((unsigned)r | ((unsigned)(c & 31) << 16));
        edges[pos] = make_int2(packed, __float_as_int(w));
    }
}

// ---------------- spmm: 2 buckets per 512-thread block, 3-stage pipeline ----
// Sub-block = 256 threads = one 32-node bucket. Halves block count and
// per-block fixed costs (LDS-zero, barriers, flush, dispatch); 8 waves/block.
#define SPMM_DS(AC, C0, W0, G0, C1, W1, G1, C2, W2, G2, C3, W3, G3)  \
    {                                                                 \
        int* a0 = &AC[C0][sub * 4];                                   \
        int* a1 = &AC[C1][sub * 4];                                   \
        int* a2 = &AC[C2][sub * 4];                                   \
        int* a3 = &AC[C3][sub * 4];                                   \
        atomicAdd(a0 + 0, __float2int_rn(W0 * G0.x));                 \
        atomicAdd(a0 + 1, __float2int_rn(W0 * G0.y));                 \
        atomicAdd(a0 + 2, __float2int_rn(W0 * G0.z));                 \
        atomicAdd(a0 + 3, __float2int_rn(W0 * G0.w));                 \
        atomicAdd(a1 + 0, __float2int_rn(W1 * G1.x));                 \
        atomicAdd(a1 + 1, __float2int_rn(W1 * G1.y));                 \
        atomicAdd(a1 + 2, __float2int_rn(W1 * G1.z));                 \
        atomicAdd(a1 + 3, __float2int_rn(W1 * G1.w));                 \
        atomicAdd(a2 + 0, __float2int_rn(W2 * G2.x));                 \
        atomicAdd(a2 + 1, __float2int_rn(W2 * G2.y));                 \
        atomicAdd(a2 + 2, __float2int_rn(W2 * G2.z));                 \
        atomicAdd(a2 + 3, __float2int_rn(W2 * G2.w));                 \
        atomicAdd(a3 + 0, __float2int_rn(W3 * G3.x));                 \
        atomicAdd(a3 + 1, __float2int_rn(W3 * G3.y));                 \
        atomicAdd(a3 + 2, __float2int_rn(W3 * G3.z));                 \
        atomicAdd(a3 + 3, __float2int_rn(W3 * G3.w));                 \
    }

__global__ __launch_bounds__(512) void k_spmm(const int* __restrict__ off_bk,
                                              const int2* __restrict__ edges,
                                              const float* __restrict__ vin,
                                              const float* __restrict__ prev,
                                              float* __restrict__ vout,
                                              float scale) {
    __shared__ int acc[2][32][33];
    for (int i = threadIdx.x; i < 2 * 32 * 33; i += 512) (&acc[0][0][0])[i] = 0;
    __syncthreads();
    int sb = threadIdx.x >> 8;               // sub-block 0/1
    int b = blockIdx.x * 2 + sb;             // bucket id
    int tid = threadIdx.x & 255;
    int group = tid >> 3, sub = tid & 7;
    int (*ac)[33] = acc[sb];
    const float4* vin4 = (const float4*)vin;
    if (b < NBK) {
        int e0 = off_bk[b], e1 = off_bk[b + 1];
        int i = e0 + group;
        if (i < e1) {
            int2 R0 = edges[i], R1 = edges[i + 32], R2 = edges[i + 64], R3 = edges[i + 96];
            float4 G0, G1, G2, G3;
            int C0 = 0, C1 = 0, C2 = 0, C3 = 0;
            float W0 = 0.f, W1 = 0.f, W2 = 0.f, W3 = 0.f;
            bool haveG = false;
            while (true) {
                int ni = i + 128;
                bool moreR = ni < e1;
                int2 N0, N1, N2, N3;
                if (moreR) {                           // stage 1: next records
                    N0 = edges[ni]; N1 = edges[ni + 32];
                    N2 = edges[ni + 64]; N3 = edges[ni + 96];
                }
                // stage 2: gather current records
                float4 g0 = vin4[((unsigned)R0.x & 0xffffu) * 8 + sub];
                float4 g1 = vin4[((unsigned)R1.x & 0xffffu) * 8 + sub];
                float4 g2 = vin4[((unsigned)R2.x & 0xffffu) * 8 + sub];
                float4 g3 = vin4[((unsigned)R3.x & 0xffffu) * 8 + sub];
                // stage 3: DS the previous batch
                if (haveG) SPMM_DS(ac, C0, W0, G0, C1, W1, G1, C2, W2, G2, C3, W3, G3);
                C0 = (unsigned)R0.x >> 16; C1 = (unsigned)R1.x >> 16;
                C2 = (unsigned)R2.x >> 16; C3 = (unsigned)R3.x >> 16;
                W0 = __int_as_float(R0.y) * SCALE_W;
                W1 = __int_as_float(R1.y) * SCALE_W;
                W2 = __int_as_float(R2.y) * SCALE_W;
                W3 = __int_as_float(R3.y) * SCALE_W;
                G0 = g0; G1 = g1; G2 = g2; G3 = g3;
                haveG = true;
                if (!moreR) break;
                R0 = N0; R1 = N1; R2 = N2; R3 = N3;
                i = ni;
            }
            SPMM_DS(ac, C0, W0, G0, C1, W1, G1, C2, W2, G2, C3, W3, G3);
        }
    }
    __syncthreads();
    if (b < NBK) {
        float sf = scale * INV_SCALE_W;
        int base = b << 5;
        int nl = tid >> 3, s4 = tid & 7;
        int n = base + nl;
        if (n < NN) {
            const int* a = &ac[nl][s4 * 4];
            float4 o;
            if (prev) {
                float4 p = ((const float4*)prev)[n * 8 + s4];
                o = make_float4(fmaf(sf, (float)a[0], -p.x),
                                fmaf(sf, (float)a[1], -p.y),
                                fmaf(sf, (float)a[2], -p.z),
                                fmaf(sf, (float)a[3], -p.w));
            } else {
                o = make_float4(sf * (float)a[0], sf * (float)a[1],
                                sf * (float)a[2], sf * (float)a[3]);
            }
            ((float4*)vout)[n * 8 + s4] = o;
        }
    }
}

// ---------------- epi1: MFMA GEMM (64 nodes x 64 outs x K=160) + GRU --------
__global__ __launch_bounds__(256) void k_epi1(
    const float* __restrict__ x, const float* __restrict__ t1,
    const float* __restrict__ t2, const float* __restrict__ t3,
    const float* __restrict__ t4, const float* __restrict__ Wx1,
    const float* __restrict__ bx1, const float* __restrict__ bh1,
    float* __restrict__ h) {
    __shared__ _Float16 T[5][MT][40];   // 25.6 KB
    __shared__ _Float16 Wt[64][168];    // 21.5 KB, [n][k]
    int n0 = blockIdx.x * MT;
    const float* bufs[5] = {x, t1, t2, t3, t4};
#pragma unroll
    for (int b = 0; b < 5; b++) {
        for (int idx = threadIdx.x; idx < MT * 8; idx += 256) {
            int r = idx >> 3, c4 = idx & 7;
            int rr = n0 + r; if (rr >= NN) rr = NN - 1;
            float4 v = *(const float4*)(bufs[b] + rr * 32 + c4 * 4);
            *(half4v*)&T[b][r][c4 * 4] =
                (half4v){(_Float16)v.x, (_Float16)v.y, (_Float16)v.z, (_Float16)v.w};
        }
    }
    const float* Wz = Wx1;
    const float* Wh = Wx1 + 2 * KORD * 32 * 32;
    for (int idx = threadIdx.x; idx < 160 * 64; idx += 256) {
        int k = idx >> 6, n = idx & 63;
        int b = k >> 5, i = k & 31;
        float w = (n < 32) ? Wz[b * 1024 + i * 32 + n]
                           : Wh[b * 1024 + i * 32 + (n - 32)];
        Wt[n][k] = (_Float16)w;
    }
    __syncthreads();
    int wave = threadIdx.x >> 6;
    int lane = threadIdx.x & 63;
    int lo = lane & 15, quad = lane >> 4;
    float4v acc[4];
#pragma unroll
    for (int t = 0; t < 4; t++) acc[t] = (float4v){0.f, 0.f, 0.f, 0.f};
#pragma unroll
    for (int b = 0; b < 5; b++) {
        half8 a = *(half8*)&T[b][wave * 16 + lo][quad * 8];
#pragma unroll
        for (int t = 0; t < 4; t++) {
            half8 bf = *(half8*)&Wt[t * 16 + lo][b * 32 + quad * 8];
            acc[t] = __builtin_amdgcn_mfma_f32_16x16x32_f16(a, bf, acc[t], 0, 0, 0);
        }
    }
    int nd_base = n0 + wave * 16 + quad * 4;
#pragma unroll
    for (int t = 0; t < 2; t++) {
        int j = t * 16 + lo;
        float bz = bx1[j] + bh1[j];
        float bhb = bx1[64 + j] + bh1[64 + j];
#pragma unroll
        for (int reg = 0; reg < 4; reg++) {
            int nd = nd_base + reg;
            if (nd < NN) {
                float zz = acc[t][reg] + bz;
                float hh = acc[t + 2][reg] + bhb;
                float z = 1.f / (1.f + __expf(-zz));
                float tt = __expf(-2.f * fabsf(hh));
                float ht = copysignf((1.f - tt) / (1.f + tt), hh);
                h[nd * 32 + j] = fmaxf((1.f - z) * ht, 0.f);
            }
        }
    }
}

// ---------------- epi2: MFMA GEMM (64 x 32 x 160) + GRU + final linear ------
__global__ __launch_bounds__(256) void k_epi2(
    const float* __restrict__ hin, const float* __restrict__ t1,
    const float* __restrict__ t2, const float* __restrict__ t3,
    const float* __restrict__ t4, const float* __restrict__ Wx2,
    const float* __restrict__ bx2, const float* __restrict__ bh2,
    const float* __restrict__ Wl, const float* __restrict__ bl,
    float* __restrict__ out) {
    __shared__ _Float16 T[5][MT][40];   // 25.6 KB
    __shared__ _Float16 Wt[32][168];    // 10.8 KB
    __shared__ float H2[MT][17];
    int n0 = blockIdx.x * MT;
    const float* bufs[5] = {hin, t1, t2, t3, t4};
#pragma unroll
    for (int b = 0; b < 5; b++) {
        for (int idx = threadIdx.x; idx < MT * 8; idx += 256) {
            int r = idx >> 3, c4 = idx & 7;
            int rr = n0 + r; if (rr >= NN) rr = NN - 1;
            float4 v = *(const float4*)(bufs[b] + rr * 32 + c4 * 4);
            *(half4v*)&T[b][r][c4 * 4] =
                (half4v){(_Float16)v.x, (_Float16)v.y, (_Float16)v.z, (_Float16)v.w};
        }
    }
    const float* Wz = Wx2;
    const float* Wh = Wx2 + 2 * KORD * 32 * 16;
    for (int idx = threadIdx.x; idx < 160 * 32; idx += 256) {
        int k = idx >> 5, n = idx & 31;
        int b = k >> 5, i = k & 31;
        float w = (n < 16) ? Wz[b * 512 + i * 16 + n]
                           : Wh[b * 512 + i * 16 + (n - 16)];
        Wt[n][k] = (_Float16)w;
    }
    __syncthreads();
    int wave = threadIdx.x >> 6;
    int lane = threadIdx.x & 63;
    int lo = lane & 15, quad = lane >> 4;
    float4v acc[2];
    acc[0] = (float4v){0.f, 0.f, 0.f, 0.f};
    acc[1] = (float4v){0.f, 0.f, 0.f, 0.f};
#pragma unroll
    for (int b = 0; b < 5; b++) {
        half8 a = *(half8*)&T[b][wave * 16 + lo][quad * 8];
#pragma unroll
        for (int t = 0; t < 2; t++) {
            half8 bf = *(half8*)&Wt[t * 16 + lo][b * 32 + quad * 8];
            acc[t] = __builtin_amdgcn_mfma_f32_16x16x32_f16(a, bf, acc[t], 0, 0, 0);
        }
    }
    {
        int j = lo;
        float bz = bx2[j] + bh2[j];
        float bhb = bx2[32 + j] + bh2[32 + j];
        int ndl_base = wave * 16 + quad * 4;
#pragma unroll
        for (int reg = 0; reg < 4; reg++) {
            float zz = acc[0][reg] + bz;
            float hh = acc[1][reg] + bhb;
            float z = 1.f / (1.f + __expf(-zz));
            float tt = __expf(-2.f * fabsf(hh));
            float ht = copysignf((1.f - tt) / (1.f + tt), hh);
            H2[ndl_base + reg][j] = fmaxf((1.f - z) * ht, 0.f);
        }
    }
    __syncthreads();
    for (int idx = threadIdx.x; idx < MT * 12; idx += 256) {
        int n = idx / 12, p = idx % 12;
        int gn = n0 + n;
        if (gn < NN) {
            float o = bl[p];
#pragma unroll
            for (int jj = 0; jj < 16; jj++) o = fmaf(H2[n][jj], Wl[p * 16 + jj], o);
            out[gn * 12 + p] = o;
        }
    }
}

// ---------------- launch ----------------

extern "C" void kernel_launch(void* const* d_in, const int* in_sizes, int n_in,
                              void* d_out, int out_size, void* d_ws, size_t ws_size,
                              hipStream_t stream) {
    const float* x   = (const float*)d_in[0];
    const int*   ei  = (const int*)d_in[1];
    const float* ew  = (const float*)d_in[2];
    const float* Wx1 = (const float*)d_in[3];
    const float* bx1 = (const float*)d_in[4];
    const float* bh1 = (const float*)d_in[6];
    const float* Wx2 = (const float*)d_in[7];
    const float* bx2 = (const float*)d_in[8];
    const float* bh2 = (const float*)d_in[10];
    const float* Wl  = (const float*)d_in[11];
    const float* bl  = (const float*)d_in[12];
    float* out = (float*)d_out;

    float* ws     = (float*)d_ws;
    float* dis    = ws;                         // 50048 floats
    int*   bh     = (int*)(ws + 50048);         // NCH*NBP = 409600 ints
    int*   tot    = bh + NCH * NBP;             // NBP ints
    int*   off_bk = tot + NBP;                  // NBP ints
    int2*  edges  = (int2*)(off_bk + NBP);      // PADE int2 (padded buckets)
    float* T1     = (float*)(edges + PADE);     // NN*32 floats each
    float* T2     = T1 + NN * 32;
    float* T3     = T2 + NN * 32;
    float* T4     = T3 + NN * 32;
    float* hb     = T4 + NN * 32;
    int*   deg_g  = (int*)T1;  // 256*QTR ints (T1+T2 region, dead before spmm)

    const int gS = (NBK + 1) / 2;   // 782 spmm blocks (2 buckets each)

    k_deg  <<<256, 1024, 0, stream>>>(ei, ew, deg_g);
    k_dis2 <<<NB, 256, 0, stream>>>(deg_g, dis);
    k_bhist<<<NCH, 1024, 0, stream>>>(ei, bh);
    k_btot <<<7, 256, 0, stream>>>(bh, tot);
    k_bscan1<<<1, 1024, 0, stream>>>(tot, off_bk);
    k_bcur <<<7, 256, 0, stream>>>(bh, off_bk);
    k_pad  <<<NBK, 128, 0, stream>>>(off_bk, tot, edges);
    k_cperm<<<NCH, 1024, 0, stream>>>(ei, ew, dis, bh, edges);

    // ---- cell 1: v = x ----
    k_spmm<<<gS, 512, 0, stream>>>(off_bk, edges, x,  nullptr, T1, 1.f);
    k_spmm<<<gS, 512, 0, stream>>>(off_bk, edges, T1, x,       T2, 2.f);
    k_spmm<<<gS, 512, 0, stream>>>(off_bk, edges, T2, T1,      T3, 2.f);
    k_spmm<<<gS, 512, 0, stream>>>(off_bk, edges, T3, T2,      T4, 2.f);
    k_epi1<<<GE, 256, 0, stream>>>(x, T1, T2, T3, T4, Wx1, bx1, bh1, hb);

    // ---- cell 2: v = hb ----
    k_spmm<<<gS, 512, 0, stream>>>(off_bk, edges, hb, nullptr, T1, 1.f);
    k_spmm<<<gS, 512, 0, stream>>>(off_bk, edges, T1, hb,      T2, 2.f);
    k_spmm<<<gS, 512, 0, stream>>>(off_bk, edges, T2, T1,      T3, 2.f);
    k_spmm<<<gS, 512, 0, stream>>>(off_bk, edges, T3, T2,      T4, 2.f);
    k_epi2<<<GE, 256, 0, stream>>>(hb, T1, T2, T3, T4, Wx2, bx2, bh2, Wl, bl, out);
}

// Round 16
// 345.937 us; speedup vs baseline: 1.0921x; 1.0921x over previous
//
#include <hip/hip_runtime.h>
#include <math.h>

#define NN 50000
#define NE 1600000
#define KORD 5
#define NB 196          // ceil(NN/256)
#define QTR 12500       // node quarter (k_deg)
#define GE 782          // epi grid: ceil(NN/64)
#define MT 64           // epi node tile
#define NBK 1563        // ceil(NN/32) destination buckets (32 nodes each)
#define NBP 1600        // padded bucket stride
#define NCH 256         // chunks for bucket kernels (fills all CUs)
#define ECH (NE / NCH)  // 6250
#define EC4 (NE / 64)   // 25000 (k_deg chunks)
#define PADE 1800192    // edge buffer capacity (NE + NBK*128, rounded)

#define SCALE_W 2097152.0f          // 2^21 spmm fixed point
#define INV_SCALE_W (1.0f / 2097152.0f)
#define SCALE_D 4194304.0f          // 2^22 degree fixed point
#define INV_SCALE_D (1.0f / 4194304.0f)

typedef _Float16 half8 __attribute__((ext_vector_type(8)));
typedef _Float16 half4v __attribute__((ext_vector_type(4)));
typedef float float4v __attribute__((ext_vector_type(4)));

// ---------------- deg: LDS int-fixed-point weighted row histogram ----------
__global__ __launch_bounds__(1024) void k_deg(const int* __restrict__ ei,
                                              const float* __restrict__ ew,
                                              int* __restrict__ deg_g) {
    __shared__ int h[QTR];   // 50 KB
    int q = blockIdx.x >> 6, ch = blockIdx.x & 63;
    for (int i = threadIdx.x; i < QTR; i += 1024) h[i] = 0;
    __syncthreads();
    int base = ch * EC4, lo = q * QTR;
    for (int e = base + threadIdx.x; e < base + EC4; e += 1024) {
        int li = ei[e] - lo;
        if ((unsigned)li < (unsigned)QTR)
            atomicAdd(&h[li], __float2int_rn(ew[e] * SCALE_D));  // ds_add_u32
    }
    __syncthreads();
    int* outp = deg_g + blockIdx.x * QTR;
    for (int i = threadIdx.x; i < QTR; i += 1024) outp[i] = h[i];
}

__global__ __launch_bounds__(256) void k_dis2(const int* __restrict__ deg_g,
                                              float* __restrict__ dis) {
    int n = blockIdx.x * 256 + threadIdx.x;
    if (n >= NN) return;
    int q = n / QTR, i = n % QTR;
    const int* p = deg_g + (q * 64) * QTR + i;
    int s = 0;
#pragma unroll
    for (int c = 0; c < 64; c++) s += p[c * QTR];
    float d = (float)s * INV_SCALE_D;
    dis[n] = s > 0 ? rsqrtf(fmaxf(d, 1e-30f)) : 0.f;
}

// convert x (fp32) -> x16 (fp16 gather mirror)
__global__ __launch_bounds__(256) void k_cvt(const float* __restrict__ x,
                                             _Float16* __restrict__ x16) {
    int i = blockIdx.x * 256 + threadIdx.x;
    if (i < NN * 8) {
        float4 v = ((const float4*)x)[i];
        half4v h = {(_Float16)v.x, (_Float16)v.y, (_Float16)v.z, (_Float16)v.w};
        *(half4v*)(x16 + i * 4) = h;
    }
}

// ---------------- bucket histogram: bh[ch][b] ----------
__global__ __launch_bounds__(1024) void k_bhist(const int* __restrict__ ei,
                                                int* __restrict__ bh) {
    __shared__ int hist[NBK];
    int ch = blockIdx.x;
    for (int i = threadIdx.x; i < NBK; i += 1024) hist[i] = 0;
    __syncthreads();
    const int* cols = ei + NE;
    int base = ch * ECH;
    for (int e = base + threadIdx.x; e < base + ECH; e += 1024)
        atomicAdd(&hist[cols[e] >> 5], 1);
    __syncthreads();
    int* outp = bh + ch * NBP;
    for (int b = threadIdx.x; b < NBK; b += 1024) outp[b] = hist[b];
}

__global__ __launch_bounds__(256) void k_btot(const int* __restrict__ bh,
                                              int* __restrict__ tot) {
    int b = blockIdx.x * 256 + threadIdx.x;
    if (b >= NBP) return;
    int s = 0;
    if (b < NBK) {
#pragma unroll 8
        for (int ch = 0; ch < NCH; ch++) s += bh[ch * NBP + b];
    }
    tot[b] = s;
}

// one block: pair-compressed exclusive scan of PADDED totals -> off_bk
__global__ __launch_bounds__(1024) void k_bscan1(const int* __restrict__ tot,
                                                 int* __restrict__ off_bk) {
    __shared__ int s[1024];
    int t = threadIdx.x;
    int a0 = (2 * t < NBP) ? tot[2 * t] : 0;
    int a1 = (2 * t + 1 < NBP) ? tot[2 * t + 1] : 0;
    int p0 = (a0 + 127) & ~127;
    int p1 = (a1 + 127) & ~127;
    s[t] = p0 + p1;
    __syncthreads();
    for (int d = 1; d < 1024; d <<= 1) {
        int u = (t >= d) ? s[t - d] : 0;
        __syncthreads();
        s[t] += u;
        __syncthreads();
    }
    int excl = (t == 0) ? 0 : s[t - 1];
    if (2 * t < NBK) off_bk[2 * t] = excl;
    if (2 * t + 1 < NBK) off_bk[2 * t + 1] = excl + p0;
    if (t == 1023) off_bk[NBK] = s[1023];
}

__global__ __launch_bounds__(256) void k_bcur(int* __restrict__ bh,
                                              const int* __restrict__ off_bk) {
    int b = blockIdx.x * 256 + threadIdx.x;
    if (b >= NBK) return;
    int run = off_bk[b];
    for (int ch = 0; ch < NCH; ch++) {
        int v = bh[ch * NBP + b];
        bh[ch * NBP + b] = run;
        run += v;
    }
}

// fill pad region of each bucket with zero-weight sentinel edges
__global__ __launch_bounds__(128) void k_pad(const int* __restrict__ off_bk,
                                             const int* __restrict__ tot,
                                             int2* __restrict__ edges) {
    int b = blockIdx.x;
    int start = off_bk[b] + tot[b];
    int end = off_bk[b + 1];
    for (int i = start + threadIdx.x; i < end; i += 128)
        edges[i] = make_int2(0, 0);   // r=0, c_local=0, w=0.0f
}

// coarse permute: record = (r | local_c<<16, weight-bits)
__global__ __launch_bounds__(1024) void k_cperm(const int* __restrict__ ei,
                                                const float* __restrict__ ew,
                                                const float* __restrict__ dis,
                                                const int* __restrict__ bh,
                                                int2* __restrict__ edges) {
    __shared__ int cur[NBK];
    int ch = blockIdx.x;
    const int* cp = bh + ch * NBP;
    for (int b = threadIdx.x; b < NBK; b += 1024) cur[b] = cp[b];
    __syncthreads();
    int base = ch * ECH;
    for (int e = base + threadIdx.x; e < base + ECH; e += 1024) {
        int r = ei[e], c = ei[NE + e];
        float w = -dis[r] * ew[e] * dis[c];
        int pos = atomicAdd(&cur[c >> 5], 1);   // ds_add_u32, native
        int packed = (int)((unsigned)r | ((unsigned)(c & 31) << 16));
        edges[pos] = make_int2(packed, __float_as_int(w));
    }
}

// ---------------- spmm: fp16 gathers (64 B/edge), fp32 recurrence ----------
// 3-stage pipeline: records(k+1) || gather(k) || ds-add(k-1).
#define SPMM_DS(C0, W0, G0, C1, W1, G1, C2, W2, G2, C3, W3, G3)      \
    {                                                                 \
        int* a0 = &acc[C0][sub * 4];                                  \
        int* a1 = &acc[C1][sub * 4];                                  \
        int* a2 = &acc[C2][sub * 4];                                  \
        int* a3 = &acc[C3][sub * 4];                                  \
        atomicAdd(a0 + 0, __float2int_rn(W0 * (float)G0.x));          \
        atomicAdd(a0 + 1, __float2int_rn(W0 * (float)G0.y));          \
        atomicAdd(a0 + 2, __float2int_rn(W0 * (float)G0.z));          \
        atomicAdd(a0 + 3, __float2int_rn(W0 * (float)G0.w));          \
        atomicAdd(a1 + 0, __float2int_rn(W1 * (float)G1.x));          \
        atomicAdd(a1 + 1, __float2int_rn(W1 * (float)G1.y));          \
        atomicAdd(a1 + 2, __float2int_rn(W1 * (float)G1.z));          \
        atomicAdd(a1 + 3, __float2int_rn(W1 * (float)G1.w));          \
        atomicAdd(a2 + 0, __float2int_rn(W2 * (float)G2.x));          \
        atomicAdd(a2 + 1, __float2int_rn(W2 * (float)G2.y));          \
        atomicAdd(a2 + 2, __float2int_rn(W2 * (float)G2.z));          \
        atomicAdd(a2 + 3, __float2int_rn(W2 * (float)G2.w));          \
        atomicAdd(a3 + 0, __float2int_rn(W3 * (float)G3.x));          \
        atomicAdd(a3 + 1, __float2int_rn(W3 * (float)G3.y));          \
        atomicAdd(a3 + 2, __float2int_rn(W3 * (float)G3.z));          \
        atomicAdd(a3 + 3, __float2int_rn(W3 * (float)G3.w));          \
    }

struct h4 { half4v v; };

__global__ __launch_bounds__(256) void k_spmm(const int* __restrict__ off_bk,
                                              const int2* __restrict__ edges,
                                              const _Float16* __restrict__ vin16,
                                              const float* __restrict__ prev,
                                              float* __restrict__ vout,
                                              _Float16* __restrict__ vout16,
                                              float scale) {
    __shared__ int acc[32][33];
    int b = blockIdx.x;
    for (int i = threadIdx.x; i < 32 * 33; i += 256) (&acc[0][0])[i] = 0;
    __syncthreads();
    int e0 = off_bk[b], e1 = off_bk[b + 1];
    int group = threadIdx.x >> 3, sub = threadIdx.x & 7;
    const h4* vin4 = (const h4*)vin16;   // 8 half4 per 32-feature row
    int i = e0 + group;
    if (i < e1) {
        int2 R0 = edges[i], R1 = edges[i + 32], R2 = edges[i + 64], R3 = edges[i + 96];
        half4v G0, G1, G2, G3;
        int C0 = 0, C1 = 0, C2 = 0, C3 = 0;
        float W0 = 0.f, W1 = 0.f, W2 = 0.f, W3 = 0.f;
        bool haveG = false;
        while (true) {
            int ni = i + 128;
            bool moreR = ni < e1;
            int2 N0, N1, N2, N3;
            if (moreR) {                           // stage 1: next records
                N0 = edges[ni]; N1 = edges[ni + 32];
                N2 = edges[ni + 64]; N3 = edges[ni + 96];
            }
            // stage 2: gather current records (fp16, 8 B/lane)
            half4v g0 = vin4[((unsigned)R0.x & 0xffffu) * 8 + sub].v;
            half4v g1 = vin4[((unsigned)R1.x & 0xffffu) * 8 + sub].v;
            half4v g2 = vin4[((unsigned)R2.x & 0xffffu) * 8 + sub].v;
            half4v g3 = vin4[((unsigned)R3.x & 0xffffu) * 8 + sub].v;
            // stage 3: DS the previous batch
            if (haveG) SPMM_DS(C0, W0, G0, C1, W1, G1, C2, W2, G2, C3, W3, G3);
            C0 = (unsigned)R0.x >> 16; C1 = (unsigned)R1.x >> 16;
            C2 = (unsigned)R2.x >> 16; C3 = (unsigned)R3.x >> 16;
            W0 = __int_as_float(R0.y) * SCALE_W;
            W1 = __int_as_float(R1.y) * SCALE_W;
            W2 = __int_as_float(R2.y) * SCALE_W;
            W3 = __int_as_float(R3.y) * SCALE_W;
            G0 = g0; G1 = g1; G2 = g2; G3 = g3;
            haveG = true;
            if (!moreR) break;
            R0 = N0; R1 = N1; R2 = N2; R3 = N3;
            i = ni;
        }
        SPMM_DS(C0, W0, G0, C1, W1, G1, C2, W2, G2, C3, W3, G3);
    }
    __syncthreads();
    float sf = scale * INV_SCALE_W;
    int base = b << 5;
    int nl = threadIdx.x >> 3, s4 = threadIdx.x & 7;
    int n = base + nl;
    if (n < NN) {
        const int* a = &acc[nl][s4 * 4];
        float4 o;
        if (prev) {
            float4 p = ((const float4*)prev)[n * 8 + s4];
            o = make_float4(fmaf(sf, (float)a[0], -p.x),
                            fmaf(sf, (float)a[1], -p.y),
                            fmaf(sf, (float)a[2], -p.z),
                            fmaf(sf, (float)a[3], -p.w));
        } else {
            o = make_float4(sf * (float)a[0], sf * (float)a[1],
                            sf * (float)a[2], sf * (float)a[3]);
        }
        if (vout) ((float4*)vout)[n * 8 + s4] = o;  // fp32 chain (skippable for T4)
        half4v oh = {(_Float16)o.x, (_Float16)o.y, (_Float16)o.z, (_Float16)o.w};
        *(half4v*)(vout16 + n * 32 + s4 * 4) = oh;  // fp16 gather/epi mirror
    }
}

// ---------------- epi1: MFMA GEMM (64 nodes x 64 outs x K=160) + GRU --------
// Inputs are fp16 mirrors; stage half8 directly into LDS (no convert).
__global__ __launch_bounds__(256) void k_epi1(
    const _Float16* __restrict__ x16, const _Float16* __restrict__ t1,
    const _Float16* __restrict__ t2, const _Float16* __restrict__ t3,
    const _Float16* __restrict__ t4, const float* __restrict__ Wx1,
    const float* __restrict__ bx1, const float* __restrict__ bh1,
    float* __restrict__ h, _Float16* __restrict__ h16) {
    __shared__ _Float16 T[5][MT][40];   // 25.6 KB
    __shared__ _Float16 Wt[64][168];    // 21.5 KB, [n][k]
    int n0 = blockIdx.x * MT;
    const _Float16* bufs[5] = {x16, t1, t2, t3, t4};
#pragma unroll
    for (int b = 0; b < 5; b++) {
        for (int idx = threadIdx.x; idx < MT * 4; idx += 256) {
            int r = idx >> 2, c8 = idx & 3;
            int rr = n0 + r; if (rr >= NN) rr = NN - 1;
            half8 v = *(const half8*)(bufs[b] + rr * 32 + c8 * 8);
            *(half8*)&T[b][r][c8 * 8] = v;
        }
    }
    const float* Wz = Wx1;
    const float* Wh = Wx1 + 2 * KORD * 32 * 32;
    for (int idx = threadIdx.x; idx < 160 * 64; idx += 256) {
        int k = idx >> 6, n = idx & 63;
        int b = k >> 5, i = k & 31;
        float w = (n < 32) ? Wz[b * 1024 + i * 32 + n]
                           : Wh[b * 1024 + i * 32 + (n - 32)];
        Wt[n][k] = (_Float16)w;
    }
    __syncthreads();
    int wave = threadIdx.x >> 6;
    int lane = threadIdx.x & 63;
    int lo = lane & 15, quad = lane >> 4;
    float4v acc[4];
#pragma unroll
    for (int t = 0; t < 4; t++) acc[t] = (float4v){0.f, 0.f, 0.f, 0.f};
#pragma unroll
    for (int b = 0; b < 5; b++) {
        half8 a = *(half8*)&T[b][wave * 16 + lo][quad * 8];
#pragma unroll
        for (int t = 0; t < 4; t++) {
            half8 bf = *(half8*)&Wt[t * 16 + lo][b * 32 + quad * 8];
            acc[t] = __builtin_amdgcn_mfma_f32_16x16x32_f16(a, bf, acc[t], 0, 0, 0);
        }
    }
    int nd_base = n0 + wave * 16 + quad * 4;
#pragma unroll
    for (int t = 0; t < 2; t++) {
        int j = t * 16 + lo;
        float bz = bx1[j] + bh1[j];
        float bhb = bx1[64 + j] + bh1[64 + j];
#pragma unroll
        for (int reg = 0; reg < 4; reg++) {
            int nd = nd_base + reg;
            if (nd < NN) {
                float zz = acc[t][reg] + bz;
                float hh = acc[t + 2][reg] + bhb;
                float z = 1.f / (1.f + __expf(-zz));
                float tt = __expf(-2.f * fabsf(hh));
                float ht = copysignf((1.f - tt) / (1.f + tt), hh);
                float v = fmaxf((1.f - z) * ht, 0.f);
                h[nd * 32 + j] = v;
                h16[nd * 32 + j] = (_Float16)v;
            }
        }
    }
}

// ---------------- epi2: MFMA GEMM (64 x 32 x 160) + GRU + final linear ------
__global__ __launch_bounds__(256) void k_epi2(
    const _Float16* __restrict__ h16, const _Float16* __restrict__ t1,
    const _Float16* __restrict__ t2, const _Float16* __restrict__ t3,
    const _Float16* __restrict__ t4, const float* __restrict__ Wx2,
    const float* __restrict__ bx2, const float* __restrict__ bh2,
    const float* __restrict__ Wl, const float* __restrict__ bl,
    float* __restrict__ out) {
    __shared__ _Float16 T[5][MT][40];   // 25.6 KB
    __shared__ _Float16 Wt[32][168];    // 10.8 KB
    __shared__ float H2[MT][17];
    int n0 = blockIdx.x * MT;
    const _Float16* bufs[5] = {h16, t1, t2, t3, t4};
#pragma unroll
    for (int b = 0; b < 5; b++) {
        for (int idx = threadIdx.x; idx < MT * 4; idx += 256) {
            int r = idx >> 2, c8 = idx & 3;
            int rr = n0 + r; if (rr >= NN) rr = NN - 1;
            half8 v = *(const half8*)(bufs[b] + rr * 32 + c8 * 8);
            *(half8*)&T[b][r][c8 * 8] = v;
        }
    }
    const float* Wz = Wx2;
    const float* Wh = Wx2 + 2 * KORD * 32 * 16;
    for (int idx = threadIdx.x; idx < 160 * 32; idx += 256) {
        int k = idx >> 5, n = idx & 31;
        int b = k >> 5, i = k & 31;
        float w = (n < 16) ? Wz[b * 512 + i * 16 + n]
                           : Wh[b * 512 + i * 16 + (n - 16)];
        Wt[n][k] = (_Float16)w;
    }
    __syncthreads();
    int wave = threadIdx.x >> 6;
    int lane = threadIdx.x & 63;
    int lo = lane & 15, quad = lane >> 4;
    float4v acc[2];
    acc[0] = (float4v){0.f, 0.f, 0.f, 0.f};
    acc[1] = (float4v){0.f, 0.f, 0.f, 0.f};
#pragma unroll
    for (int b = 0; b < 5; b++) {
        half8 a = *(half8*)&T[b][wave * 16 + lo][quad * 8];
#pragma unroll
        for (int t = 0; t < 2; t++) {
            half8 bf = *(half8*)&Wt[t * 16 + lo][b * 32 + quad * 8];
            acc[t] = __builtin_amdgcn_mfma_f32_16x16x32_f16(a, bf, acc[t], 0, 0, 0);
        }
    }
    {
        int j = lo;
        float bz = bx2[j] + bh2[j];
        float bhb = bx2[32 + j] + bh2[32 + j];
        int ndl_base = wave * 16 + quad * 4;
#pragma unroll
        for (int reg = 0; reg < 4; reg++) {
            float zz = acc[0][reg] + bz;
            float hh = acc[1][reg] + bhb;
            float z = 1.f / (1.f + __expf(-zz));
            float tt = __expf(-2.f * fabsf(hh));
            float ht = copysignf((1.f - tt) / (1.f + tt), hh);
            H2[ndl_base + reg][j] = fmaxf((1.f - z) * ht, 0.f);
        }
    }
    __syncthreads();
    for (int idx = threadIdx.x; idx < MT * 12; idx += 256) {
        int n = idx / 12, p = idx % 12;
        int gn = n0 + n;
        if (gn < NN) {
            float o = bl[p];
#pragma unroll
            for (int jj = 0; jj < 16; jj++) o = fmaf(H2[n][jj], Wl[p * 16 + jj], o);
            out[gn * 12 + p] = o;
        }
    }
}

// ---------------- launch ----------------

extern "C" void kernel_launch(void* const* d_in, const int* in_sizes, int n_in,
                              void* d_out, int out_size, void* d_ws, size_t ws_size,
                              hipStream_t stream) {
    const float* x   = (const float*)d_in[0];
    const int*   ei  = (const int*)d_in[1];
    const float* ew  = (const float*)d_in[2];
    const float* Wx1 = (const float*)d_in[3];
    const float* bx1 = (const float*)d_in[4];
    const float* bh1 = (const float*)d_in[6];
    const float* Wx2 = (const float*)d_in[7];
    const float* bx2 = (const float*)d_in[8];
    const float* bh2 = (const float*)d_in[10];
    const float* Wl  = (const float*)d_in[11];
    const float* bl  = (const float*)d_in[12];
    float* out = (float*)d_out;

    float* ws     = (float*)d_ws;
    float* dis    = ws;                         // 50048 floats
    int*   bh     = (int*)(ws + 50048);         // NCH*NBP = 409600 ints
    int*   tot    = bh + NCH * NBP;             // NBP ints
    int*   off_bk = tot + NBP;                  // NBP ints
    int2*  edges  = (int2*)(off_bk + NBP);      // PADE int2 (padded buckets)
    float* T1     = (float*)(edges + PADE);     // fp32 chain buffers
    float* T2     = T1 + NN * 32;
    float* T3     = T2 + NN * 32;
    float* hb     = T3 + NN * 32;
    _Float16* x16 = (_Float16*)(hb + NN * 32);  // fp16 mirrors
    _Float16* t1h = x16 + NN * 32;
    _Float16* t2h = t1h + NN * 32;
    _Float16* t3h = t2h + NN * 32;
    _Float16* t4h = t3h + NN * 32;
    _Float16* hbh = t4h + NN * 32;
    int*   deg_g  = (int*)T1;  // 256*QTR ints (T1+T2 region, dead before spmm)

    k_deg  <<<256, 1024, 0, stream>>>(ei, ew, deg_g);
    k_dis2 <<<NB, 256, 0, stream>>>(deg_g, dis);
    k_cvt  <<<(NN * 8 + 255) / 256, 256, 0, stream>>>(x, x16);
    k_bhist<<<NCH, 1024, 0, stream>>>(ei, bh);
    k_btot <<<7, 256, 0, stream>>>(bh, tot);
    k_bscan1<<<1, 1024, 0, stream>>>(tot, off_bk);
    k_bcur <<<7, 256, 0, stream>>>(bh, off_bk);
    k_pad  <<<NBK, 128, 0, stream>>>(off_bk, tot, edges);
    k_cperm<<<NCH, 1024, 0, stream>>>(ei, ew, dis, bh, edges);

    // ---- cell 1: v = x ----
    k_spmm<<<NBK, 256, 0, stream>>>(off_bk, edges, x16, nullptr, T1, t1h, 1.f);
    k_spmm<<<NBK, 256, 0, stream>>>(off_bk, edges, t1h, x,      T2, t2h, 2.f);
    k_spmm<<<NBK, 256, 0, stream>>>(off_bk, edges, t2h, T1,     T3, t3h, 2.f);
    k_spmm<<<NBK, 256, 0, stream>>>(off_bk, edges, t3h, T2, nullptr, t4h, 2.f);
    k_epi1<<<GE, 256, 0, stream>>>(x16, t1h, t2h, t3h, t4h, Wx1, bx1, bh1, hb, hbh);

    // ---- cell 2: v = hb ----
    k_spmm<<<NBK, 256, 0, stream>>>(off_bk, edges, hbh, nullptr, T1, t1h, 1.f);
    k_spmm<<<NBK, 256, 0, stream>>>(off_bk, edges, t1h, hb,     T2, t2h, 2.f);
    k_spmm<<<NBK, 256, 0, stream>>>(off_bk, edges, t2h, T1,     T3, t3h, 2.f);
    k_spmm<<<NBK, 256, 0, stream>>>(off_bk, edges, t3h, T2, nullptr, t4h, 2.f);
    k_epi2<<<GE, 256, 0, stream>>>(hbh, t1h, t2h, t3h, t4h, Wx2, bx2, bh2, Wl, bl, out);
}